// Round 9
// baseline (674.024 us; speedup 1.0000x reference)
//
#include <hip/hip_runtime.h>
#include <hip/hip_bf16.h>
#include <hip/hip_fp16.h>

#define EMB 16
#define RPB 391      // right-rows per bucket (512 buckets cover NR<=200192)
#define MAXNB 512
#define CAP 16384    // payload slots/bucket; mean load ~7812, uniform random => never exceeds
#define EPT 4        // edges per 16-lane group per iteration (ILP)
#define NBIN_BLOCKS 512

typedef _Float16 half8 __attribute__((ext_vector_type(8)));

// ---------------------------------------------------------------------------
// Kernel 1: both node transforms in one launch; outputs fp16 tables.
//   n < NL : TL[n] = fp16(left[n] @ Wl.T + bl)     (b_left folded in)
//   else   : TR[n-NL] = fp16(right[n-NL] @ Wr.T)
// ---------------------------------------------------------------------------
__global__ __launch_bounds__(256) void node_transform2_kernel(
    const float* __restrict__ left, const float* __restrict__ right,
    const float* __restrict__ Wl, const float* __restrict__ bl,
    const float* __restrict__ Wr,
    _Float16* __restrict__ TL, _Float16* __restrict__ TR, int NL, int NR) {
    __shared__ float sWl[EMB * EMB], sWr[EMB * EMB], sbl[EMB];
    if (threadIdx.x < EMB * EMB) {
        sWl[threadIdx.x] = Wl[threadIdx.x];
        sWr[threadIdx.x] = Wr[threadIdx.x];
    }
    if (threadIdx.x < EMB) sbl[threadIdx.x] = bl[threadIdx.x];
    __syncthreads();

    int n = blockIdx.x * blockDim.x + threadIdx.x;
    if (n >= NL + NR) return;
    bool is_left = (n < NL);
    const float* X = is_left ? (left + (size_t)n * EMB)
                             : (right + (size_t)(n - NL) * EMB);
    _Float16* Y = is_left ? (TL + (size_t)n * EMB)
                          : (TR + (size_t)(n - NL) * EMB);
    const float* sW = is_left ? sWl : sWr;

    float x[EMB];
    const float4* xp = (const float4*)X;
    float4 x0 = xp[0], x1 = xp[1], x2 = xp[2], x3 = xp[3];
    x[0] = x0.x; x[1] = x0.y; x[2] = x0.z; x[3] = x0.w;
    x[4] = x1.x; x[5] = x1.y; x[6] = x1.z; x[7] = x1.w;
    x[8] = x2.x; x[9] = x2.y; x[10] = x2.z; x[11] = x2.w;
    x[12] = x3.x; x[13] = x3.y; x[14] = x3.z; x[15] = x3.w;

    float y[EMB];
#pragma unroll
    for (int j = 0; j < EMB; ++j) {
        float a = is_left ? sbl[j] : 0.0f;
#pragma unroll
        for (int k = 0; k < EMB; ++k) a = fmaf(sW[j * EMB + k], x[k], a);
        y[j] = a;
    }

    half8* yp = (half8*)Y;
    half8 h0, h1;
#pragma unroll
    for (int k = 0; k < 8; ++k) h0[k] = (_Float16)y[k];
#pragma unroll
    for (int k = 0; k < 8; ++k) h1[k] = (_Float16)y[8 + k];
    yp[0] = h0;
    yp[1] = h1;
}

// ---------------------------------------------------------------------------
// Kernel 2: counting-sort edges into right-node buckets (b = r / RPB).
// Per block: LDS histogram over its contiguous edge range -> one global
// reservation atomic per non-empty bucket -> scatter 8B payloads
// {l | rlo<<18, ef} into the reserved (contiguous, block-exclusive) slots.
// Block-exclusive contiguous destination ranges => XCD L2 write-merges the
// scatter into streaming writes (no RMW, no read-for-ownership cost).
// ---------------------------------------------------------------------------
__global__ __launch_bounds__(256) void binning_kernel(
    const int* __restrict__ idx, const float* __restrict__ ef,
    uint2* __restrict__ payload, unsigned int* __restrict__ gcursor,
    int E, int NB, int per) {
    __shared__ unsigned int hist[MAXNB];
    __shared__ unsigned int cur[MAXNB];
    int tid = threadIdx.x;
    for (int b = tid; b < NB; b += 256) hist[b] = 0;
    __syncthreads();

    int start = blockIdx.x * per;
    int end = min(E, start + per);

    for (int e = start + tid; e < end; e += 256) {
        int r = idx[E + e];
        atomicAdd(&hist[r / RPB], 1u);
    }
    __syncthreads();

    for (int b = tid; b < NB; b += 256) {
        unsigned int h = hist[b];
        cur[b] = h ? atomicAdd(&gcursor[b], h) : 0u;
    }
    __syncthreads();

    for (int e = start + tid; e < end; e += 256) {
        int l = idx[e];
        int r = idx[E + e];
        int b = r / RPB;
        int rlo = r - b * RPB;
        unsigned int slot = atomicAdd(&cur[b], 1u);
        if (slot < CAP)
            payload[(size_t)b * CAP + slot] =
                make_uint2((unsigned)l | ((unsigned)rlo << 18),
                           __float_as_uint(ef[e]));
    }
}

// ---------------------------------------------------------------------------
// Kernel 3: per-bucket edge accumulation + fused epilogue. One block per
// bucket of RPB right-nodes. TR window lives in LDS (no global TR gather);
// S/cnt accumulate in LDS via ds_add (no global atomics). W_final/b_final
// are hoisted to the epilogue: agg = S @ Wf.T + cnt*bf. The only random
// global stream left is the TL gather: 1 x 32B transaction per edge.
// ---------------------------------------------------------------------------
__global__ __launch_bounds__(256) void bucket_compute_kernel(
    const uint2* __restrict__ payload, const unsigned int* __restrict__ gcursor,
    const _Float16* __restrict__ TL, const _Float16* __restrict__ TRg,
    const float* __restrict__ right, const float* __restrict__ wedge,
    const float* __restrict__ Wf, const float* __restrict__ bfi,
    const float* __restrict__ Wp, const float* __restrict__ bp,
    const float* __restrict__ Wo1, const float* __restrict__ bo1,
    const float* __restrict__ Wo2, const float* __restrict__ bo2,
    float* __restrict__ out, int NR) {
    __shared__ _Float16 sTR[RPB * EMB];   // 12.5 KB
    __shared__ float sS[RPB * EMB];       // 25.0 KB
    __shared__ float sCnt[RPB];           //  1.6 KB
    __shared__ float sWf[256], sWp[256], sWo1[512], sWo2[256];
    __shared__ float sbf[16], sbp[16], sbo1[16], sbo2[16], swe[16];

    int tid = threadIdx.x;
    int b = blockIdx.x;
    int row0 = b * RPB;
    int rows = min(RPB, NR - row0);

    if (tid < 256) { sWf[tid] = Wf[tid]; sWp[tid] = Wp[tid]; sWo2[tid] = Wo2[tid]; }
    for (int i = tid; i < 512; i += 256) sWo1[i] = Wo1[i];
    if (tid < 16) {
        sbf[tid] = bfi[tid]; sbp[tid] = bp[tid];
        sbo1[tid] = bo1[tid]; sbo2[tid] = bo2[tid];
        swe[tid] = wedge[tid];
    }
    {   // TR window preload (rows*16 fp16 = rows*8 dwords, coalesced)
        const unsigned int* src = (const unsigned int*)(TRg + (size_t)row0 * EMB);
        unsigned int* dst = (unsigned int*)sTR;
        for (int i = tid; i < rows * 8; i += 256) dst[i] = src[i];
    }
    for (int i = tid; i < rows * EMB; i += 256) sS[i] = 0.0f;
    for (int i = tid; i < rows; i += 256) sCnt[i] = 0.0f;
    __syncthreads();

    int count = min((int)gcursor[b], CAP);
    int g = tid >> 4;
    int t = tid & 15;
    float we = swe[t];
    const uint2* pay = payload + (size_t)b * CAP;

    int iters = (count + 16 * EPT - 1) / (16 * EPT);
    for (int it = 0; it < iters; ++it) {
        int ebase = it * (16 * EPT) + g;
        uint2 p[EPT];
        bool val[EPT];
#pragma unroll
        for (int m = 0; m < EPT; ++m) {
            int e = ebase + m * 16;
            val[m] = (e < count);
            p[m] = pay[val[m] ? e : 0];
        }
        _Float16 tlv[EPT];
        int rl[EPT];
        float efq[EPT];
#pragma unroll
        for (int m = 0; m < EPT; ++m) {
            int l = p[m].x & 0x3FFFF;
            rl[m] = (int)(p[m].x >> 18);
            efq[m] = __uint_as_float(p[m].y);
            tlv[m] = TL[(size_t)l * EMB + t];   // the one random gather
        }
#pragma unroll
        for (int m = 0; m < EPT; ++m) {
            float v = fmaxf((float)tlv[m] + (float)sTR[rl[m] * EMB + t]
                            + efq[m] * we, 0.0f);
            if (val[m]) {
                atomicAdd(&sS[rl[m] * EMB + t], v);      // ds_add_f32
                if (t == 0) atomicAdd(&sCnt[rl[m]], 1.0f);
            }
        }
    }
    __syncthreads();

    // Fused epilogue: agg = S@Wf.T + cnt*bf ; post ; cat right ; out MLP
    for (int i = tid; i < rows; i += 256) {
        int gr = row0 + i;
        float s[EMB];
        {
            const float4* sp = (const float4*)(sS + i * EMB);
            float4 a0 = sp[0], a1 = sp[1], a2 = sp[2], a3 = sp[3];
            s[0] = a0.x; s[1] = a0.y; s[2] = a0.z; s[3] = a0.w;
            s[4] = a1.x; s[5] = a1.y; s[6] = a1.z; s[7] = a1.w;
            s[8] = a2.x; s[9] = a2.y; s[10] = a2.z; s[11] = a2.w;
            s[12] = a3.x; s[13] = a3.y; s[14] = a3.z; s[15] = a3.w;
        }
        float c = sCnt[i];

        float ra[EMB];
#pragma unroll
        for (int j = 0; j < EMB; ++j) {
            float a = c * sbf[j];
#pragma unroll
            for (int k = 0; k < EMB; ++k) a = fmaf(sWf[j * EMB + k], s[k], a);
            ra[j] = fmaxf(a, 0.0f);
        }

        float pch[EMB];
#pragma unroll
        for (int j = 0; j < EMB; ++j) {
            float a = sbp[j];
#pragma unroll
            for (int k = 0; k < EMB; ++k) a = fmaf(sWp[j * EMB + k], ra[k], a);
            pch[j] = a;
        }

        float rf[EMB];
        {
            const float4* rp = (const float4*)(right + (size_t)gr * EMB);
            float4 a0 = rp[0], a1 = rp[1], a2 = rp[2], a3 = rp[3];
            rf[0] = a0.x; rf[1] = a0.y; rf[2] = a0.z; rf[3] = a0.w;
            rf[4] = a1.x; rf[5] = a1.y; rf[6] = a1.z; rf[7] = a1.w;
            rf[8] = a2.x; rf[9] = a2.y; rf[10] = a2.z; rf[11] = a2.w;
            rf[12] = a3.x; rf[13] = a3.y; rf[14] = a3.z; rf[15] = a3.w;
        }

        float h[EMB];
#pragma unroll
        for (int j = 0; j < EMB; ++j) {
            float a = sbo1[j];
#pragma unroll
            for (int k = 0; k < EMB; ++k) a = fmaf(sWo1[j * 32 + k], pch[k], a);
#pragma unroll
            for (int k = 0; k < EMB; ++k) a = fmaf(sWo1[j * 32 + 16 + k], rf[k], a);
            h[j] = fmaxf(a, 0.0f);
        }

        float o[EMB];
#pragma unroll
        for (int j = 0; j < EMB; ++j) {
            float a = sbo2[j];
#pragma unroll
            for (int k = 0; k < EMB; ++k) a = fmaf(sWo2[j * EMB + k], h[k], a);
            o[j] = a;
        }

        float4* op = (float4*)(out + (size_t)gr * EMB);
        op[0] = make_float4(o[0], o[1], o[2], o[3]);
        op[1] = make_float4(o[4], o[5], o[6], o[7]);
        op[2] = make_float4(o[8], o[9], o[10], o[11]);
        op[3] = make_float4(o[12], o[13], o[14], o[15]);
    }
}

// ---------------------------------------------------------------------------
extern "C" void kernel_launch(void* const* d_in, const int* in_sizes, int n_in,
                              void* d_out, int out_size, void* d_ws, size_t ws_size,
                              hipStream_t stream) {
    const float* left  = (const float*)d_in[0];
    const float* ef    = (const float*)d_in[1];
    const float* right = (const float*)d_in[2];
    const int*   eidx  = (const int*)d_in[3];
    const float* W_left  = (const float*)d_in[4];
    const float* b_left  = (const float*)d_in[5];
    const float* W_edge  = (const float*)d_in[6];
    const float* W_right = (const float*)d_in[7];
    const float* W_final = (const float*)d_in[8];
    const float* b_final = (const float*)d_in[9];
    const float* W_post  = (const float*)d_in[10];
    const float* b_post  = (const float*)d_in[11];
    const float* W_out1  = (const float*)d_in[12];
    const float* b_out1  = (const float*)d_in[13];
    const float* W_out2  = (const float*)d_in[14];
    const float* b_out2  = (const float*)d_in[15];

    const int NL = in_sizes[0] / EMB;
    const int NR = in_sizes[2] / EMB;
    const int E  = in_sizes[1];
    const int NB = (NR + RPB - 1) / RPB;   // 512 for NR=200000

    // Workspace: TL16 | TR16 | payload | gcursor
    size_t tl_b  = (size_t)NL * EMB * 2;
    size_t tr_b  = (size_t)NR * EMB * 2;
    size_t pay_b = (size_t)NB * CAP * sizeof(uint2);
    char* ws = (char*)d_ws;
    _Float16* TL = (_Float16*)ws;
    _Float16* TR = (_Float16*)(ws + tl_b);
    uint2* payload = (uint2*)(ws + tl_b + tr_b);
    unsigned int* gcursor = (unsigned int*)(ws + tl_b + tr_b + pay_b);

    // Zero bucket cursors (ws is re-poisoned before every launch)
    (void)hipMemsetAsync(gcursor, 0, (size_t)NB * 4, stream);

    // Node transforms -> fp16 tables
    node_transform2_kernel<<<(NL + NR + 255) / 256, 256, 0, stream>>>(
        left, right, W_left, b_left, W_right, TL, TR, NL, NR);

    // Counting-sort edges into buckets
    {
        int per = (E + NBIN_BLOCKS - 1) / NBIN_BLOCKS;
        binning_kernel<<<NBIN_BLOCKS, 256, 0, stream>>>(
            eidx, ef, payload, gcursor, E, NB, per);
    }

    // Per-bucket accumulate + fused epilogue
    bucket_compute_kernel<<<NB, 256, 0, stream>>>(
        payload, gcursor, TL, TR, right, W_edge,
        W_final, b_final, W_post, b_post,
        W_out1, b_out1, W_out2, b_out2, (float*)d_out, NR);
}

// Round 10
// 640.254 us; speedup vs baseline: 1.0527x; 1.0527x over previous
//
#include <hip/hip_runtime.h>
#include <hip/hip_bf16.h>
#include <hip/hip_fp16.h>

#define EMB 16
#define NB 1024      // right-node buckets
#define RPB 196      // rows per bucket (1024*196 = 200704 >= NR)
#define CAP 4608     // payload slots/bucket; mean ~3906, sigma ~62 -> never exceeds
#define EPT 4        // edges per 16-lane group per iteration (ILP)
#define NBIN 256     // binning blocks: per-block bucket runs ~15 edges -> L2 write-merge
#define TRS 18       // sTR row stride (halfs), padded vs 16 to spread banks
#define SSS 17       // sS row stride (floats), padded vs 16 to spread banks

typedef _Float16 half8 __attribute__((ext_vector_type(8)));

// ---------------------------------------------------------------------------
// Kernel 1: both node transforms in one launch; outputs fp16 tables.
//   n < NL : TL[n] = fp16(left[n] @ Wl.T + bl)     (b_left folded in)
//   else   : TR[n-NL] = fp16(right[n-NL] @ Wr.T)
// ---------------------------------------------------------------------------
__global__ __launch_bounds__(256) void node_transform2_kernel(
    const float* __restrict__ left, const float* __restrict__ right,
    const float* __restrict__ Wl, const float* __restrict__ bl,
    const float* __restrict__ Wr,
    _Float16* __restrict__ TL, _Float16* __restrict__ TR, int NL, int NR) {
    __shared__ float sWl[EMB * EMB], sWr[EMB * EMB], sbl[EMB];
    if (threadIdx.x < EMB * EMB) {
        sWl[threadIdx.x] = Wl[threadIdx.x];
        sWr[threadIdx.x] = Wr[threadIdx.x];
    }
    if (threadIdx.x < EMB) sbl[threadIdx.x] = bl[threadIdx.x];
    __syncthreads();

    int n = blockIdx.x * blockDim.x + threadIdx.x;
    if (n >= NL + NR) return;
    bool is_left = (n < NL);
    const float* X = is_left ? (left + (size_t)n * EMB)
                             : (right + (size_t)(n - NL) * EMB);
    _Float16* Y = is_left ? (TL + (size_t)n * EMB)
                          : (TR + (size_t)(n - NL) * EMB);
    const float* sW = is_left ? sWl : sWr;

    float x[EMB];
    const float4* xp = (const float4*)X;
    float4 x0 = xp[0], x1 = xp[1], x2 = xp[2], x3 = xp[3];
    x[0] = x0.x; x[1] = x0.y; x[2] = x0.z; x[3] = x0.w;
    x[4] = x1.x; x[5] = x1.y; x[6] = x1.z; x[7] = x1.w;
    x[8] = x2.x; x[9] = x2.y; x[10] = x2.z; x[11] = x2.w;
    x[12] = x3.x; x[13] = x3.y; x[14] = x3.z; x[15] = x3.w;

    float y[EMB];
#pragma unroll
    for (int j = 0; j < EMB; ++j) {
        float a = is_left ? sbl[j] : 0.0f;
#pragma unroll
        for (int k = 0; k < EMB; ++k) a = fmaf(sW[j * EMB + k], x[k], a);
        y[j] = a;
    }

    half8* yp = (half8*)Y;
    half8 h0, h1;
#pragma unroll
    for (int k = 0; k < 8; ++k) h0[k] = (_Float16)y[k];
#pragma unroll
    for (int k = 0; k < 8; ++k) h1[k] = (_Float16)y[8 + k];
    yp[0] = h0;
    yp[1] = h1;
}

// ---------------------------------------------------------------------------
// Kernel 2: counting-sort edges into right-node buckets (b = r / RPB).
// Per block: LDS histogram over its contiguous edge range -> one global
// reservation atomic per bucket -> scatter 8B payloads {l | rlo<<18, ef}
// into reserved (contiguous, block-exclusive) slots. 256 blocks => ~15
// edges per bucket per block => runs of ~2 cache lines => L2 write-merge.
// ---------------------------------------------------------------------------
__global__ __launch_bounds__(256) void binning_kernel(
    const int* __restrict__ idx, const float* __restrict__ ef,
    uint2* __restrict__ payload, unsigned int* __restrict__ gcursor,
    int E, int per) {
    __shared__ unsigned int hist[NB];
    __shared__ unsigned int cur[NB];
    int tid = threadIdx.x;
    for (int b = tid; b < NB; b += 256) hist[b] = 0;
    __syncthreads();

    int start = blockIdx.x * per;
    int end = min(E, start + per);

    for (int e = start + tid; e < end; e += 256)
        atomicAdd(&hist[idx[E + e] / RPB], 1u);
    __syncthreads();

    for (int b = tid; b < NB; b += 256) {
        unsigned int h = hist[b];
        cur[b] = h ? atomicAdd(&gcursor[b], h) : 0u;
    }
    __syncthreads();

    for (int e = start + tid; e < end; e += 256) {
        int l = idx[e];
        int r = idx[E + e];
        int b = r / RPB;
        int rlo = r - b * RPB;
        unsigned int slot = atomicAdd(&cur[b], 1u);
        if (slot < CAP)
            payload[(size_t)b * CAP + slot] =
                make_uint2((unsigned)l | ((unsigned)rlo << 18),
                           __float_as_uint(ef[e]));
    }
}

// ---------------------------------------------------------------------------
// Kernel 3: per-bucket edge accumulation ONLY (epilogue split out to keep
// VGPR low — R9's fused epilogue cost 204 VGPRs -> 11% occupancy). TR window
// in padded LDS (no global TR gather); S/cnt accumulate in padded LDS via
// ds_add (no global atomics); dense streaming writeout of S/cnt. The only
// random global stream: 1 x 32B TL gather per edge.
// ---------------------------------------------------------------------------
__global__ __launch_bounds__(256) void bucket_compute_kernel(
    const uint2* __restrict__ payload, const unsigned int* __restrict__ gcursor,
    const _Float16* __restrict__ TL, const _Float16* __restrict__ TRg,
    const float* __restrict__ wedge,
    float* __restrict__ S, float* __restrict__ cnt, int NR) {
    __shared__ _Float16 sTR[RPB * TRS];   // 7.1 KB
    __shared__ float sS[RPB * SSS];       // 13.3 KB
    __shared__ float sCnt[RPB];           // 0.8 KB
    __shared__ float swe[EMB];

    int tid = threadIdx.x;
    int b = blockIdx.x;
    int row0 = b * RPB;
    int rows = min(RPB, NR - row0);

    if (tid < EMB) swe[tid] = wedge[tid];
    for (int i = tid; i < rows * EMB; i += 256)
        sTR[(i >> 4) * TRS + (i & 15)] = TRg[(size_t)row0 * EMB + i];
    for (int i = tid; i < RPB * SSS; i += 256) sS[i] = 0.0f;
    for (int i = tid; i < RPB; i += 256) sCnt[i] = 0.0f;
    __syncthreads();

    int count = min((int)gcursor[b], CAP);
    int g = tid >> 4;
    int t = tid & 15;
    float we = swe[t];
    const uint2* pay = payload + (size_t)b * CAP;

    int iters = (count + 16 * EPT - 1) / (16 * EPT);
    for (int it = 0; it < iters; ++it) {
        int e0 = it * (16 * EPT) + g;
        uint2 p[EPT];
        bool val[EPT];
#pragma unroll
        for (int m = 0; m < EPT; ++m) {
            int e = e0 + m * 16;
            val[m] = (e < count);
            p[m] = pay[val[m] ? e : 0];
        }
        _Float16 tlv[EPT];
        int rl[EPT];
        float efq[EPT];
#pragma unroll
        for (int m = 0; m < EPT; ++m) {
            int l = p[m].x & 0x3FFFF;
            rl[m] = (int)(p[m].x >> 18);
            efq[m] = __uint_as_float(p[m].y);
            tlv[m] = TL[(size_t)l * EMB + t];   // the one random gather
        }
#pragma unroll
        for (int m = 0; m < EPT; ++m) {
            float v = fmaxf((float)tlv[m] + (float)sTR[rl[m] * TRS + t]
                            + efq[m] * we, 0.0f);
            if (val[m]) {
                atomicAdd(&sS[rl[m] * SSS + t], v);      // ds_add_f32
                if (t == 0) atomicAdd(&sCnt[rl[m]], 1.0f);
            }
        }
    }
    __syncthreads();

    // Dense streaming writeout
    for (int i = tid; i < rows * EMB; i += 256)
        S[(size_t)row0 * EMB + i] = sS[(i >> 4) * SSS + (i & 15)];
    for (int i = tid; i < rows; i += 256) cnt[row0 + i] = sCnt[i];
}

// ---------------------------------------------------------------------------
// Kernel 4: per-right-node epilogue.
// agg = S@Wf.T + cnt*bf ; post = relu(agg)@Wp.T+bp ; cat right ; MLP ; out
// ---------------------------------------------------------------------------
__global__ __launch_bounds__(256) void epilogue_kernel(
    const float* __restrict__ S, const float* __restrict__ cnt,
    const float* __restrict__ right,
    const float* __restrict__ Wf, const float* __restrict__ bf,
    const float* __restrict__ Wp, const float* __restrict__ bp,
    const float* __restrict__ Wo1, const float* __restrict__ bo1,
    const float* __restrict__ Wo2, const float* __restrict__ bo2,
    float* __restrict__ out, int N) {
    __shared__ float sWf[256], sWp[256], sWo2[256], sWo1[512];
    __shared__ float sbf[16], sbp[16], sbo1[16], sbo2[16];
    for (int i = threadIdx.x; i < 256; i += blockDim.x) {
        sWf[i] = Wf[i]; sWp[i] = Wp[i]; sWo2[i] = Wo2[i];
    }
    for (int i = threadIdx.x; i < 512; i += blockDim.x) sWo1[i] = Wo1[i];
    if (threadIdx.x < 16) {
        sbf[threadIdx.x] = bf[threadIdx.x];
        sbp[threadIdx.x] = bp[threadIdx.x];
        sbo1[threadIdx.x] = bo1[threadIdx.x];
        sbo2[threadIdx.x] = bo2[threadIdx.x];
    }
    __syncthreads();

    int n = blockIdx.x * blockDim.x + threadIdx.x;
    if (n >= N) return;

    float s[EMB];
    {
        const float4* sp = (const float4*)(S + (size_t)n * EMB);
        float4 a0 = sp[0], a1 = sp[1], a2 = sp[2], a3 = sp[3];
        s[0] = a0.x; s[1] = a0.y; s[2] = a0.z; s[3] = a0.w;
        s[4] = a1.x; s[5] = a1.y; s[6] = a1.z; s[7] = a1.w;
        s[8] = a2.x; s[9] = a2.y; s[10] = a2.z; s[11] = a2.w;
        s[12] = a3.x; s[13] = a3.y; s[14] = a3.z; s[15] = a3.w;
    }
    float c = cnt[n];

    float ra[EMB];
#pragma unroll
    for (int j = 0; j < EMB; ++j) {
        float a = c * sbf[j];
#pragma unroll
        for (int k = 0; k < EMB; ++k) a = fmaf(sWf[j * EMB + k], s[k], a);
        ra[j] = fmaxf(a, 0.0f);
    }

    float p[EMB];
#pragma unroll
    for (int j = 0; j < EMB; ++j) {
        float a = sbp[j];
#pragma unroll
        for (int k = 0; k < EMB; ++k) a = fmaf(sWp[j * EMB + k], ra[k], a);
        p[j] = a;
    }

    float rf[EMB];
    {
        const float4* rp = (const float4*)(right + (size_t)n * EMB);
        float4 a0 = rp[0], a1 = rp[1], a2 = rp[2], a3 = rp[3];
        rf[0] = a0.x; rf[1] = a0.y; rf[2] = a0.z; rf[3] = a0.w;
        rf[4] = a1.x; rf[5] = a1.y; rf[6] = a1.z; rf[7] = a1.w;
        rf[8] = a2.x; rf[9] = a2.y; rf[10] = a2.z; rf[11] = a2.w;
        rf[12] = a3.x; rf[13] = a3.y; rf[14] = a3.z; rf[15] = a3.w;
    }

    float h[EMB];
#pragma unroll
    for (int j = 0; j < EMB; ++j) {
        float a = sbo1[j];
#pragma unroll
        for (int k = 0; k < EMB; ++k) a = fmaf(sWo1[j * 32 + k], p[k], a);
#pragma unroll
        for (int k = 0; k < EMB; ++k) a = fmaf(sWo1[j * 32 + 16 + k], rf[k], a);
        h[j] = fmaxf(a, 0.0f);
    }

    float o[EMB];
#pragma unroll
    for (int j = 0; j < EMB; ++j) {
        float a = sbo2[j];
#pragma unroll
        for (int k = 0; k < EMB; ++k) a = fmaf(sWo2[j * EMB + k], h[k], a);
        o[j] = a;
    }

    float4* op = (float4*)(out + (size_t)n * EMB);
    op[0] = make_float4(o[0], o[1], o[2], o[3]);
    op[1] = make_float4(o[4], o[5], o[6], o[7]);
    op[2] = make_float4(o[8], o[9], o[10], o[11]);
    op[3] = make_float4(o[12], o[13], o[14], o[15]);
}

// ---------------------------------------------------------------------------
extern "C" void kernel_launch(void* const* d_in, const int* in_sizes, int n_in,
                              void* d_out, int out_size, void* d_ws, size_t ws_size,
                              hipStream_t stream) {
    const float* left  = (const float*)d_in[0];
    const float* ef    = (const float*)d_in[1];
    const float* right = (const float*)d_in[2];
    const int*   eidx  = (const int*)d_in[3];
    const float* W_left  = (const float*)d_in[4];
    const float* b_left  = (const float*)d_in[5];
    const float* W_edge  = (const float*)d_in[6];
    const float* W_right = (const float*)d_in[7];
    const float* W_final = (const float*)d_in[8];
    const float* b_final = (const float*)d_in[9];
    const float* W_post  = (const float*)d_in[10];
    const float* b_post  = (const float*)d_in[11];
    const float* W_out1  = (const float*)d_in[12];
    const float* b_out1  = (const float*)d_in[13];
    const float* W_out2  = (const float*)d_in[14];
    const float* b_out2  = (const float*)d_in[15];

    const int NL = in_sizes[0] / EMB;
    const int NR = in_sizes[2] / EMB;
    const int E  = in_sizes[1];
    const int nb = (NR + RPB - 1) / RPB;   // <= NB

    // Workspace: TL16 | TR16 | S | cnt | payload | gcursor
    size_t tl_b  = (size_t)NL * EMB * 2;
    size_t tr_b  = (size_t)NR * EMB * 2;
    size_t s_b   = (size_t)nb * RPB * EMB * 4;
    size_t c_b   = (size_t)nb * RPB * 4;
    size_t pay_b = (size_t)NB * CAP * sizeof(uint2);
    char* ws = (char*)d_ws;
    _Float16* TL = (_Float16*)ws;
    _Float16* TR = (_Float16*)(ws + tl_b);
    float* S = (float*)(ws + tl_b + tr_b);
    float* cnt = (float*)(ws + tl_b + tr_b + s_b);
    uint2* payload = (uint2*)(ws + tl_b + tr_b + s_b + c_b);
    unsigned int* gcursor = (unsigned int*)(ws + tl_b + tr_b + s_b + c_b + pay_b);

    // Zero bucket cursors only (S/cnt are fully written by bucket kernel)
    (void)hipMemsetAsync(gcursor, 0, (size_t)NB * 4, stream);

    // Node transforms -> fp16 tables
    node_transform2_kernel<<<(NL + NR + 255) / 256, 256, 0, stream>>>(
        left, right, W_left, b_left, W_right, TL, TR, NL, NR);

    // Counting-sort edges into buckets
    {
        int per = (E + NBIN - 1) / NBIN;
        binning_kernel<<<NBIN, 256, 0, stream>>>(eidx, ef, payload, gcursor, E, per);
    }

    // Per-bucket accumulate (S, cnt to global, streaming)
    bucket_compute_kernel<<<nb, 256, 0, stream>>>(
        payload, gcursor, TL, TR, W_edge, S, cnt, NR);

    // Epilogue
    epilogue_kernel<<<(NR + 255) / 256, 256, 0, stream>>>(
        S, cnt, right, W_final, b_final, W_post, b_post,
        W_out1, b_out1, W_out2, b_out2, (float*)d_out, NR);
}

// Round 11
// 352.607 us; speedup vs baseline: 1.9115x; 1.8158x over previous
//
#include <hip/hip_runtime.h>
#include <hip/hip_bf16.h>
#include <hip/hip_fp16.h>

#define EMB 16
#define EPT 4   // edges per 16-lane group (ILP batch)

typedef _Float16 half8 __attribute__((ext_vector_type(8)));

// ---------------------------------------------------------------------------
// Kernel 1: both node transforms in one launch; outputs fp16 tables.
//   n < NL : TL[n] = fp16(left[n] @ Wl.T + bl)     (b_left folded in)
//   else   : TR[n-NL] = fp16(right[n-NL] @ Wr.T)
// ---------------------------------------------------------------------------
__global__ __launch_bounds__(256) void node_transform2_kernel(
    const float* __restrict__ left, const float* __restrict__ right,
    const float* __restrict__ Wl, const float* __restrict__ bl,
    const float* __restrict__ Wr,
    _Float16* __restrict__ TL, _Float16* __restrict__ TR, int NL, int NR) {
    __shared__ float sWl[EMB * EMB], sWr[EMB * EMB], sbl[EMB];
    if (threadIdx.x < EMB * EMB) {
        sWl[threadIdx.x] = Wl[threadIdx.x];
        sWr[threadIdx.x] = Wr[threadIdx.x];
    }
    if (threadIdx.x < EMB) sbl[threadIdx.x] = bl[threadIdx.x];
    __syncthreads();

    int n = blockIdx.x * blockDim.x + threadIdx.x;
    if (n >= NL + NR) return;
    bool is_left = (n < NL);
    const float* X = is_left ? (left + (size_t)n * EMB)
                             : (right + (size_t)(n - NL) * EMB);
    _Float16* Y = is_left ? (TL + (size_t)n * EMB)
                          : (TR + (size_t)(n - NL) * EMB);
    const float* sW = is_left ? sWl : sWr;

    float x[EMB];
    const float4* xp = (const float4*)X;
    float4 x0 = xp[0], x1 = xp[1], x2 = xp[2], x3 = xp[3];
    x[0] = x0.x; x[1] = x0.y; x[2] = x0.z; x[3] = x0.w;
    x[4] = x1.x; x[5] = x1.y; x[6] = x1.z; x[7] = x1.w;
    x[8] = x2.x; x[9] = x2.y; x[10] = x2.z; x[11] = x2.w;
    x[12] = x3.x; x[13] = x3.y; x[14] = x3.z; x[15] = x3.w;

    float y[EMB];
#pragma unroll
    for (int j = 0; j < EMB; ++j) {
        float a = is_left ? sbl[j] : 0.0f;
#pragma unroll
        for (int k = 0; k < EMB; ++k) a = fmaf(sW[j * EMB + k], x[k], a);
        y[j] = a;
    }

    half8* yp = (half8*)Y;
    half8 h0, h1;
#pragma unroll
    for (int k = 0; k < 8; ++k) h0[k] = (_Float16)y[k];
#pragma unroll
    for (int k = 0; k < 8; ++k) h1[k] = (_Float16)y[8 + k];
    yp[0] = h0;
    yp[1] = h1;
}

// ---------------------------------------------------------------------------
// Kernel 2: per-edge fused message + scatter, EPT edges per 16-lane group.
// Measured structure (R5-R8): the kernel sits at the platform's random
// 32-64B transaction ceiling (~59G trans/s) with 3 random transactions per
// edge: TL gather + TR gather + packed-fp16 atomic. Concurrency (R6), gather
// bytes (R7), and atomic bytes (R8) all proven non-binding.
//   pre_t = TL[l][t] + TR[r][t] + ef*wedge[t]   (b_left folded into TL)
//   w_t   = bf[t] + sum_k Wf[t][k] * relu(pre)_k   (ds_swizzle broadcast;
//           folding Wf/bf per edge eliminates the cnt atomic — R4's win)
// Lane t<8 packs (w_{2t}, w_{2t+1}) via ds_bpermute and issues one 32B
// global_atomic_pk_add_f16 per edge.
// ---------------------------------------------------------------------------
__global__ __launch_bounds__(256) void edge_scatter_kernel(
    const int* __restrict__ idx, const float* __restrict__ ef,
    const _Float16* __restrict__ TL, const _Float16* __restrict__ TR,
    const float* __restrict__ wedge, const float* __restrict__ Wf,
    const float* __restrict__ bf, __half2* __restrict__ S, int E, int G) {
    int gid = blockIdx.x * blockDim.x + threadIdx.x;
    int g = gid >> 4;
    int t = gid & 15;

    int lane = threadIdx.x & 63;
    int gbase = lane & 48;                       // 16-lane group base in wave
    int bp0 = (gbase | ((2 * t) & 15)) << 2;     // byte addr for ds_bpermute
    int bp1 = (gbase | ((2 * t + 1) & 15)) << 2;

    // Per-lane constants (L1-resident after first wave)
    float we = wedge[t];
    float bft = bf[t];
    float wrow[EMB];
    {
        const float4* wp = (const float4*)(Wf + t * EMB);
        float4 w0 = wp[0], w1 = wp[1], w2 = wp[2], w3 = wp[3];
        wrow[0] = w0.x; wrow[1] = w0.y; wrow[2] = w0.z; wrow[3] = w0.w;
        wrow[4] = w1.x; wrow[5] = w1.y; wrow[6] = w1.z; wrow[7] = w1.w;
        wrow[8] = w2.x; wrow[9] = w2.y; wrow[10] = w2.z; wrow[11] = w2.w;
        wrow[12] = w3.x; wrow[13] = w3.y; wrow[14] = w3.z; wrow[15] = w3.w;
    }

    int l[EPT], r[EPT];
    float efv[EPT];
    bool valid[EPT];
#pragma unroll
    for (int j = 0; j < EPT; ++j) {
        int e = g + j * G;
        valid[j] = (e < E);
        int ec = valid[j] ? e : 0;
        l[j] = idx[ec];
        r[j] = idx[E + ec];
        efv[j] = ef[ec];
    }

    _Float16 ah[EPT], bh[EPT];
#pragma unroll
    for (int j = 0; j < EPT; ++j) {
        ah[j] = TL[(size_t)l[j] * EMB + t];
        bh[j] = TR[(size_t)r[j] * EMB + t];
    }

#pragma unroll
    for (int j = 0; j < EPT; ++j) {
        float v = fmaxf((float)ah[j] + (float)bh[j] + efv[j] * we, 0.0f);
        int vi = __float_as_int(v);
        float w = bft;
#define SWIZ_STEP(K)                                                          \
        {                                                                     \
            float vk = __int_as_float(                                        \
                __builtin_amdgcn_ds_swizzle(vi, ((K) << 5) | 0x10));          \
            w = fmaf(wrow[K], vk, w);                                         \
        }
        SWIZ_STEP(0)  SWIZ_STEP(1)  SWIZ_STEP(2)  SWIZ_STEP(3)
        SWIZ_STEP(4)  SWIZ_STEP(5)  SWIZ_STEP(6)  SWIZ_STEP(7)
        SWIZ_STEP(8)  SWIZ_STEP(9)  SWIZ_STEP(10) SWIZ_STEP(11)
        SWIZ_STEP(12) SWIZ_STEP(13) SWIZ_STEP(14) SWIZ_STEP(15)
#undef SWIZ_STEP

        // Pack (w_{2t}, w_{2t+1}) into lane t (t<8) and issue pk fp16 atomic.
        int wi = __float_as_int(w);
        float w0 = __int_as_float(__builtin_amdgcn_ds_bpermute(bp0, wi));
        float w1 = __int_as_float(__builtin_amdgcn_ds_bpermute(bp1, wi));
        if (valid[j] && t < 8) {
            __half2 hv = __floats2half2_rn(w0, w1);
            unsafeAtomicAdd(S + (size_t)r[j] * 8 + t, hv);
        }
    }
}

// ---------------------------------------------------------------------------
// Kernel 3: per-right-node epilogue. S (fp16) is the aggregated message.
// ---------------------------------------------------------------------------
__global__ __launch_bounds__(256) void epilogue_kernel(
    const _Float16* __restrict__ S, const float* __restrict__ right,
    const float* __restrict__ Wp, const float* __restrict__ bp,
    const float* __restrict__ Wo1, const float* __restrict__ bo1,
    const float* __restrict__ Wo2, const float* __restrict__ bo2,
    float* __restrict__ out, int N) {
    __shared__ float sWp[256], sWo2[256], sWo1[512];
    __shared__ float sbp[16], sbo1[16], sbo2[16];
    for (int i = threadIdx.x; i < 256; i += blockDim.x) {
        sWp[i] = Wp[i]; sWo2[i] = Wo2[i];
    }
    for (int i = threadIdx.x; i < 512; i += blockDim.x) sWo1[i] = Wo1[i];
    if (threadIdx.x < 16) {
        sbp[threadIdx.x] = bp[threadIdx.x];
        sbo1[threadIdx.x] = bo1[threadIdx.x];
        sbo2[threadIdx.x] = bo2[threadIdx.x];
    }
    __syncthreads();

    int n = blockIdx.x * blockDim.x + threadIdx.x;
    if (n >= N) return;

    float ra[EMB];
    {
        const half8* sp = (const half8*)(S + (size_t)n * EMB);
        half8 a0 = sp[0], a1 = sp[1];
#pragma unroll
        for (int k = 0; k < 8; ++k) ra[k] = fmaxf((float)a0[k], 0.0f);
#pragma unroll
        for (int k = 0; k < 8; ++k) ra[8 + k] = fmaxf((float)a1[k], 0.0f);
    }

    float p[EMB];
#pragma unroll
    for (int j = 0; j < EMB; ++j) {
        float a = sbp[j];
#pragma unroll
        for (int k = 0; k < EMB; ++k) a = fmaf(sWp[j * EMB + k], ra[k], a);
        p[j] = a;
    }

    float rf[EMB];
    {
        const float4* rp = (const float4*)(right + (size_t)n * EMB);
        float4 a0 = rp[0], a1 = rp[1], a2 = rp[2], a3 = rp[3];
        rf[0] = a0.x; rf[1] = a0.y; rf[2] = a0.z; rf[3] = a0.w;
        rf[4] = a1.x; rf[5] = a1.y; rf[6] = a1.z; rf[7] = a1.w;
        rf[8] = a2.x; rf[9] = a2.y; rf[10] = a2.z; rf[11] = a2.w;
        rf[12] = a3.x; rf[13] = a3.y; rf[14] = a3.z; rf[15] = a3.w;
    }

    float h[EMB];
#pragma unroll
    for (int j = 0; j < EMB; ++j) {
        float a = sbo1[j];
#pragma unroll
        for (int k = 0; k < EMB; ++k) a = fmaf(sWo1[j * 32 + k], p[k], a);
#pragma unroll
        for (int k = 0; k < EMB; ++k) a = fmaf(sWo1[j * 32 + 16 + k], rf[k], a);
        h[j] = fmaxf(a, 0.0f);
    }

    float o[EMB];
#pragma unroll
    for (int j = 0; j < EMB; ++j) {
        float a = sbo2[j];
#pragma unroll
        for (int k = 0; k < EMB; ++k) a = fmaf(sWo2[j * EMB + k], h[k], a);
        o[j] = a;
    }

    float4* op = (float4*)(out + (size_t)n * EMB);
    op[0] = make_float4(o[0], o[1], o[2], o[3]);
    op[1] = make_float4(o[4], o[5], o[6], o[7]);
    op[2] = make_float4(o[8], o[9], o[10], o[11]);
    op[3] = make_float4(o[12], o[13], o[14], o[15]);
}

// ---------------------------------------------------------------------------
extern "C" void kernel_launch(void* const* d_in, const int* in_sizes, int n_in,
                              void* d_out, int out_size, void* d_ws, size_t ws_size,
                              hipStream_t stream) {
    const float* left  = (const float*)d_in[0];
    const float* ef    = (const float*)d_in[1];
    const float* right = (const float*)d_in[2];
    const int*   eidx  = (const int*)d_in[3];
    const float* W_left  = (const float*)d_in[4];
    const float* b_left  = (const float*)d_in[5];
    const float* W_edge  = (const float*)d_in[6];
    const float* W_right = (const float*)d_in[7];
    const float* W_final = (const float*)d_in[8];
    const float* b_final = (const float*)d_in[9];
    const float* W_post  = (const float*)d_in[10];
    const float* b_post  = (const float*)d_in[11];
    const float* W_out1  = (const float*)d_in[12];
    const float* b_out1  = (const float*)d_in[13];
    const float* W_out2  = (const float*)d_in[14];
    const float* b_out2  = (const float*)d_in[15];

    const int NL = in_sizes[0] / EMB;
    const int NR = in_sizes[2] / EMB;
    const int E  = in_sizes[1];

    // Workspace: TL16 | TR16 | S (fp16)
    size_t tl_b = (size_t)NL * EMB * 2;
    size_t tr_b = (size_t)NR * EMB * 2;
    char* ws = (char*)d_ws;
    _Float16* TL = (_Float16*)ws;
    _Float16* TR = (_Float16*)(ws + tl_b);
    _Float16* S16 = (_Float16*)(ws + tl_b + tr_b);

    // Zero the scatter accumulator (ws is re-poisoned before every launch)
    (void)hipMemsetAsync(S16, 0, (size_t)NR * EMB * 2, stream);

    // Both node transforms in one launch (b_left folded into TL)
    node_transform2_kernel<<<(NL + NR + 255) / 256, 256, 0, stream>>>(
        left, right, W_left, b_left, W_right, TL, TR, NL, NR);

    // Edge scatter: EPT edges per 16-lane group, packed fp16 atomics
    {
        int G = (E + EPT - 1) / EPT;             // number of 16-lane groups
        long long threads = (long long)G * 16;
        int blocks = (int)((threads + 255) / 256);
        edge_scatter_kernel<<<blocks, 256, 0, stream>>>(
            eidx, ef, TL, TR, W_edge, W_final, b_final, (__half2*)S16, E, G);
    }

    // Epilogue
    epilogue_kernel<<<(NR + 255) / 256, 256, 0, stream>>>(
        S16, right, W_post, b_post, W_out1, b_out1, W_out2, b_out2,
        (float*)d_out, NR);
}